// Round 6
// baseline (467.715 us; speedup 1.0000x reference)
//
#include <hip/hip_runtime.h>
#include <hip/hip_cooperative_groups.h>

namespace cg = cooperative_groups;

#define LRELU_SLOPE 0.2f

// ---------------------------------------------------------------------------
// Fused cooperative GAT (6 phases, grid.sync) with a checked launch and a
// fallback to the proven 5-kernel path (round 4, 160us) if the cooperative
// launch is refused. Round-5 lesson: 1024 blocks was exactly at the
// co-residency bound and hipLaunchCooperativeKernel silently failed -> zeros.
// Now: occupancy-query-sized grid + error check.
//
// Workspace: nodef[N float4] | cnt[N] | rowptr[N] | rank[E] | colsrc[E]
//            | total[1] | cursor[N] | consts[16]
// ---------------------------------------------------------------------------

__global__ __launch_bounds__(256, 4) void k_fused(
        const int* __restrict__ esrc, const int* __restrict__ edst,
        const float* __restrict__ x,
        const float* __restrict__ W1, const float* __restrict__ as1,
        const float* __restrict__ ad1, const float* __restrict__ b1,
        const float* __restrict__ W2, const float* __restrict__ as2,
        const float* __restrict__ ad2, const float* __restrict__ b2,
        int* __restrict__ cnt, int* __restrict__ rowptr,
        int* __restrict__ rank, int* __restrict__ colsrc,
        int* __restrict__ total, float4* __restrict__ nodef,
        float* __restrict__ out, int N, int E) {
    cg::grid_group grid = cg::this_grid();
    __shared__ float sW1[512], sB1[512], sW2[1024], sconsts[16];

    for (int t = threadIdx.x; t < 512; t += 256) { sW1[t] = W1[t]; sB1[t] = b1[t]; }
    for (int t = threadIdx.x; t < 1024; t += 256) sW2[t] = W2[t];
    if (threadIdx.x < 16) {
        int h = threadIdx.x & 7;
        const float* a = (threadIdx.x < 8) ? as1 : ad1;
        float acc = 0.f;
        #pragma unroll
        for (int f = 0; f < 64; ++f) acc += W1[h * 64 + f] * a[h * 64 + f];
        sconsts[threadIdx.x] = acc;
    }

    int tid = blockIdx.x * blockDim.x + threadIdx.x;
    int gs = gridDim.x * blockDim.x;
    int lane = threadIdx.x & 63;

    // ---- P0: zero accumulators ----
    for (int j = tid; j < N; j += gs) cnt[j] = 0;
    if (tid == 0) { *total = 0; out[0] = 0.f; out[1] = 0.f; }
    grid.sync();

    // ---- P1: in-degree histogram; atomic return value = edge rank ----
    for (int j = tid; j < E; j += gs)
        rank[j] = atomicAdd(&cnt[edst[j]], 1);
    grid.sync();

    // ---- P2: slab alloc (wave scan + one cursor atomic per wave) ----
    for (int n = tid; (n - lane) < N; n += gs) {
        int v = (n < N) ? cnt[n] : 0;
        int incl = v;
        #pragma unroll
        for (int off = 1; off < 64; off <<= 1) {
            int u = __shfl_up(incl, off);
            if (lane >= off) incl += u;
        }
        int wtot = __shfl(incl, 63);
        int base = 0;
        if (lane == 63) base = atomicAdd(total, wtot);
        base = __shfl(base, 63);
        if (n < N) rowptr[n] = base + incl - v;
    }
    grid.sync();

    // ---- P3: scatter src ids — atomic-free via rank ----
    for (int j = tid; j < E; j += gs)
        colsrc[rowptr[edst[j]] + rank[j]] = esrc[j];
    grid.sync();

    // ---- P4: layer-1 gather + rank-1 expansion + ReLU + 512x2 GEMV ----
    for (int n = tid; n < N; n += gs) {
        float cs[8], cd[8];
        #pragma unroll
        for (int h = 0; h < 8; ++h) { cs[h] = sconsts[h]; cd[h] = sconsts[8 + h]; }
        float xd = x[n];
        float den[8], num[8];
        #pragma unroll
        for (int h = 0; h < 8; ++h) {        // self-loop
            float e = fmaf(xd, cs[h], xd * cd[h]);
            e = e > 0.f ? e : LRELU_SLOPE * e;
            float ex = __expf(e);
            den[h] = ex; num[h] = ex * xd;
        }
        int start = rowptr[n], deg = cnt[n];
        for (int k = 0; k < deg; ++k) {
            float xs = x[colsrc[start + k]];
            #pragma unroll
            for (int h = 0; h < 8; ++h) {
                float e = fmaf(xs, cs[h], xd * cd[h]);
                e = e > 0.f ? e : LRELU_SLOPE * e;
                float ex = __expf(e);
                den[h] += ex; num[h] += ex * xs;
            }
        }
        float h20 = 0.f, h21 = 0.f;
        #pragma unroll
        for (int h = 0; h < 8; ++h) {
            float sh = num[h] / (den[h] + 1e-16f);
            for (int f = 0; f < 64; ++f) {
                int idx = h * 64 + f;
                float v = fmaf(sW1[idx], sh, sB1[idx]);
                v = fmaxf(v, 0.f);
                h20 = fmaf(v, sW2[2 * idx], h20);
                h21 = fmaf(v, sW2[2 * idx + 1], h21);
            }
        }
        float as_ = h20 * as2[0] + h21 * as2[1];
        float ad_ = h20 * ad2[0] + h21 * ad2[1];
        float4 o; o.x = h20; o.y = h21; o.z = as_; o.w = ad_;
        nodef[n] = o;
    }
    grid.sync();

    // ---- P5: layer-2 gather + log_softmax + mean reduction ----
    float l0 = 0.f, l1 = 0.f;
    for (int n = tid; n < N; n += gs) {
        float4 fd = nodef[n];
        float e = fd.z + fd.w;                    // self-loop
        e = e > 0.f ? e : LRELU_SLOPE * e;
        float ex = __expf(e);
        float den = ex, n0 = ex * fd.x, n1 = ex * fd.y;
        int start = rowptr[n], deg = cnt[n];
        for (int k = 0; k < deg; ++k) {
            float4 fs = nodef[colsrc[start + k]];
            e = fs.z + fd.w;
            e = e > 0.f ? e : LRELU_SLOPE * e;
            ex = __expf(e);
            den += ex; n0 += ex * fs.x; n1 += ex * fs.y;
        }
        float inv = 1.f / (den + 1e-16f);
        float o0 = n0 * inv + b2[0];
        float o1 = n1 * inv + b2[1];
        float m = fmaxf(o0, o1);
        float z0 = o0 - m, z1 = o1 - m;
        float lse = logf(__expf(z0) + __expf(z1));
        l0 += z0 - lse; l1 += z1 - lse;
    }
    #pragma unroll
    for (int off = 32; off; off >>= 1) {
        l0 += __shfl_down(l0, off);
        l1 += __shfl_down(l1, off);
    }
    __shared__ float w0[4], w1[4];
    int wid = threadIdx.x >> 6;
    if (lane == 0) { w0[wid] = l0; w1[wid] = l1; }
    __syncthreads();
    if (threadIdx.x == 0) {
        float s0 = w0[0] + w0[1] + w0[2] + w0[3];
        float s1 = w1[0] + w1[1] + w1[2] + w1[3];
        float invN = 1.f / (float)N;
        atomicAdd(&out[0], s0 * invN);
        atomicAdd(&out[1], s1 * invN);
    }
}

// ------------------------- fallback path (round 4) -------------------------

__global__ void k_hist(const int* __restrict__ edst, int* __restrict__ cnt, int E,
                       const float* __restrict__ W1,
                       const float* __restrict__ as1,
                       const float* __restrict__ ad1,
                       float* __restrict__ consts,
                       float* __restrict__ out) {
    if (blockIdx.x == 0) {
        if (threadIdx.x < 16) {
            int h = threadIdx.x & 7;
            const float* a = (threadIdx.x < 8) ? as1 : ad1;
            float acc = 0.f;
            #pragma unroll
            for (int f = 0; f < 64; ++f) acc += W1[h * 64 + f] * a[h * 64 + f];
            consts[threadIdx.x] = acc;
        }
        if (threadIdx.x == 0) { out[0] = 0.f; out[1] = 0.f; }
    }
    int i = blockIdx.x * blockDim.x + threadIdx.x;
    int stride = gridDim.x * blockDim.x;
    for (int j = i; j < E; j += stride) atomicAdd(&cnt[edst[j]], 1);
}

__global__ __launch_bounds__(256) void k_alloc(const int* __restrict__ cnt,
                                               int* __restrict__ rowptr,
                                               int* __restrict__ cursor,
                                               int* __restrict__ total, int N) {
    int n = blockIdx.x * blockDim.x + threadIdx.x;
    int lane = threadIdx.x & 63;
    int v = (n < N) ? cnt[n] : 0;
    int incl = v;
    #pragma unroll
    for (int off = 1; off < 64; off <<= 1) {
        int u = __shfl_up(incl, off);
        if (lane >= off) incl += u;
    }
    int wtot = __shfl(incl, 63);
    int base = 0;
    if (lane == 63) base = atomicAdd(total, wtot);
    base = __shfl(base, 63);
    int start = base + incl - v;
    if (n < N) { rowptr[n] = start; cursor[n] = start; }
}

__global__ void k_scatter(const int* __restrict__ esrc, const int* __restrict__ edst,
                          int* __restrict__ cursor, int* __restrict__ colsrc, int E) {
    int i = blockIdx.x * blockDim.x + threadIdx.x;
    int stride = gridDim.x * blockDim.x;
    for (int j = i; j < E; j += stride) {
        int d = edst[j];
        int pos = atomicAdd(&cursor[d], 1);
        colsrc[pos] = esrc[j];
    }
}

__global__ __launch_bounds__(256) void k_gather1(
        const int* __restrict__ rowptr, const int* __restrict__ cnt,
        const int* __restrict__ colsrc,
        const float* __restrict__ x, const float* __restrict__ consts,
        const float* __restrict__ W1, const float* __restrict__ b1,
        const float* __restrict__ W2,
        const float* __restrict__ as2, const float* __restrict__ ad2,
        float4* __restrict__ nodef, int N) {
    __shared__ float sW1[512], sB1[512], sW2[1024];
    for (int t = threadIdx.x; t < 512; t += 256) { sW1[t] = W1[t]; sB1[t] = b1[t]; }
    for (int t = threadIdx.x; t < 1024; t += 256) sW2[t] = W2[t];
    __syncthreads();
    int n = blockIdx.x * blockDim.x + threadIdx.x;
    if (n >= N) return;
    float cs[8], cd[8];
    #pragma unroll
    for (int h = 0; h < 8; ++h) { cs[h] = consts[h]; cd[h] = consts[8 + h]; }
    float xd = x[n];
    float den[8], num[8];
    #pragma unroll
    for (int h = 0; h < 8; ++h) {
        float e = fmaf(xd, cs[h], xd * cd[h]);
        e = e > 0.f ? e : LRELU_SLOPE * e;
        float ex = __expf(e);
        den[h] = ex; num[h] = ex * xd;
    }
    int start = rowptr[n], deg = cnt[n];
    for (int k = 0; k < deg; ++k) {
        int s = colsrc[start + k];
        float xs = x[s];
        #pragma unroll
        for (int h = 0; h < 8; ++h) {
            float e = fmaf(xs, cs[h], xd * cd[h]);
            e = e > 0.f ? e : LRELU_SLOPE * e;
            float ex = __expf(e);
            den[h] += ex; num[h] += ex * xs;
        }
    }
    float h20 = 0.f, h21 = 0.f;
    #pragma unroll
    for (int h = 0; h < 8; ++h) {
        float sh = num[h] / (den[h] + 1e-16f);
        for (int f = 0; f < 64; ++f) {
            int idx = h * 64 + f;
            float v = fmaf(sW1[idx], sh, sB1[idx]);
            v = fmaxf(v, 0.f);
            h20 = fmaf(v, sW2[2 * idx], h20);
            h21 = fmaf(v, sW2[2 * idx + 1], h21);
        }
    }
    float as_ = h20 * as2[0] + h21 * as2[1];
    float ad_ = h20 * ad2[0] + h21 * ad2[1];
    float4 o; o.x = h20; o.y = h21; o.z = as_; o.w = ad_;
    nodef[n] = o;
}

__global__ __launch_bounds__(256) void k_gather2(
        const int* __restrict__ rowptr, const int* __restrict__ cnt,
        const int* __restrict__ colsrc,
        const float4* __restrict__ nodef, const float* __restrict__ b2,
        float* __restrict__ out, int N) {
    int n = blockIdx.x * blockDim.x + threadIdx.x;
    float l0 = 0.f, l1 = 0.f;
    if (n < N) {
        float4 fd = nodef[n];
        float e = fd.z + fd.w;
        e = e > 0.f ? e : LRELU_SLOPE * e;
        float ex = __expf(e);
        float den = ex, n0 = ex * fd.x, n1 = ex * fd.y;
        int start = rowptr[n], deg = cnt[n];
        for (int k = 0; k < deg; ++k) {
            float4 fs = nodef[colsrc[start + k]];
            e = fs.z + fd.w;
            e = e > 0.f ? e : LRELU_SLOPE * e;
            ex = __expf(e);
            den += ex; n0 += ex * fs.x; n1 += ex * fs.y;
        }
        float inv = 1.f / (den + 1e-16f);
        float o0 = n0 * inv + b2[0];
        float o1 = n1 * inv + b2[1];
        float m = fmaxf(o0, o1);
        float z0 = o0 - m, z1 = o1 - m;
        float lse = logf(__expf(z0) + __expf(z1));
        l0 = z0 - lse; l1 = z1 - lse;
    }
    #pragma unroll
    for (int off = 32; off; off >>= 1) {
        l0 += __shfl_down(l0, off);
        l1 += __shfl_down(l1, off);
    }
    __shared__ float w0[4], w1[4];
    int wid = threadIdx.x >> 6, lane = threadIdx.x & 63;
    if (lane == 0) { w0[wid] = l0; w1[wid] = l1; }
    __syncthreads();
    if (threadIdx.x == 0) {
        float s0 = w0[0] + w0[1] + w0[2] + w0[3];
        float s1 = w1[0] + w1[1] + w1[2] + w1[3];
        float invN = 1.f / (float)N;
        atomicAdd(&out[0], s0 * invN);
        atomicAdd(&out[1], s1 * invN);
    }
}

extern "C" void kernel_launch(void* const* d_in, const int* in_sizes, int n_in,
                              void* d_out, int out_size, void* d_ws, size_t ws_size,
                              hipStream_t stream) {
    const float* x   = (const float*)d_in[0];
    const int*   ei  = (const int*)d_in[1];
    const float* W1  = (const float*)d_in[2];
    const float* as1 = (const float*)d_in[3];
    const float* ad1 = (const float*)d_in[4];
    const float* b1  = (const float*)d_in[5];
    const float* W2  = (const float*)d_in[6];
    const float* as2 = (const float*)d_in[7];
    const float* ad2 = (const float*)d_in[8];
    const float* b2  = (const float*)d_in[9];
    int N = in_sizes[0];       // 50000
    int E = in_sizes[1] / 2;   // 400000
    float* out = (float*)d_out;

    char* ws = (char*)d_ws;
    float4* nodef  = (float4*)ws;                    // N*16B
    int*    cnt    = (int*)(ws + (size_t)N * 16);    // N
    int*    rowptr = cnt + N;                        // N
    int*    rank   = rowptr + N;                     // E
    int*    colsrc = rank + E;                       // E
    int*    total  = colsrc + E;                     // 1
    int*    cursor = total + 1;                      // N  (fallback only)
    float*  consts = (float*)(cursor + N);           // 16 (fallback only)

    const int* esrc = ei;
    const int* edst = ei + E;

    // Size the cooperative grid from the runtime's own occupancy model
    // (deterministic host-side queries; capture-safe — no stream ops).
    int numCU = 256, maxPerCU = 0;
    hipDeviceGetAttribute(&numCU, hipDeviceAttributeMultiprocessorCount, 0);
    hipOccupancyMaxActiveBlocksPerMultiprocessor(&maxPerCU,
                                                 (const void*)k_fused, 256, 0);
    int gridBlocks = maxPerCU > 0 ? maxPerCU * numCU : 0;
    if (gridBlocks > 1024) gridBlocks = 1024;

    hipError_t err = hipErrorUnknown;
    if (gridBlocks > 0) {
        void* args[] = {
            (void*)&esrc, (void*)&edst, (void*)&x,
            (void*)&W1, (void*)&as1, (void*)&ad1, (void*)&b1,
            (void*)&W2, (void*)&as2, (void*)&ad2, (void*)&b2,
            (void*)&cnt, (void*)&rowptr, (void*)&rank, (void*)&colsrc,
            (void*)&total, (void*)&nodef, (void*)&out, (void*)&N, (void*)&E,
        };
        err = hipLaunchCooperativeKernel((const void*)k_fused,
                                         dim3(gridBlocks), dim3(256),
                                         args, 0, stream);
    }

    if (err != hipSuccess) {
        // Fallback: proven round-4 multi-kernel path (same math).
        hipMemsetAsync(cnt, 0, (size_t)(2 * N + 1) * sizeof(int), stream); // cnt..total? (cnt,rowptr) not needed; zero cnt+rowptr+? keep simple: cnt[N] + rowptr? — only cnt and total must be 0
        // Note: the memset above zeroes cnt[N] and rowptr[N] and total; rowptr
        // is overwritten by k_alloc before use, so this is merely conservative.
        int eb = (E + 255) / 256;
        hipLaunchKernelGGL(k_hist, dim3(eb), dim3(256), 0, stream,
                           edst, cnt, E, W1, as1, ad1, consts, out);
        int nb = (N + 255) / 256;
        hipLaunchKernelGGL(k_alloc, dim3(nb), dim3(256), 0, stream,
                           cnt, rowptr, cursor, total, N);
        hipLaunchKernelGGL(k_scatter, dim3(eb), dim3(256), 0, stream,
                           esrc, edst, cursor, colsrc, E);
        hipLaunchKernelGGL(k_gather1, dim3(nb), dim3(256), 0, stream,
                           rowptr, cnt, colsrc, x, consts, W1, b1, W2, as2, ad2,
                           nodef, N);
        hipLaunchKernelGGL(k_gather2, dim3(nb), dim3(256), 0, stream,
                           rowptr, cnt, colsrc, nodef, b2, out, N);
    }
}

// Round 8
// 159.714 us; speedup vs baseline: 2.9285x; 2.9285x over previous
//
#include <hip/hip_runtime.h>

#define LRELU_SLOPE 0.2f
#define K_SLAB 40
#define OVF_MAX 8192

// ---------------------------------------------------------------------------
// 4-dispatch gather GAT.
// Round-6 lesson: cooperative grid.sync() costs ~100us each on gfx950 (cg
// barrier spins device-scope across 8 non-coherent XCD L2s) — kernel-launch
// boundaries are the cheap barrier (~3-5us). So: multi-kernel, but minimal.
//
// vs round 4 (160us): hist+alloc+scatter collapsed into ONE scatter pass
// using a fixed-capacity TRANSPOSED slab colsrc[rank*N + d] (K=40; in-degree
// is Poisson(8), overflow list for safety — empty in practice). Transposed
// layout makes gather reads coalesced (lane n reads colsrc[k*N+n]).
// Gather parallelism raised: 4 threads/node (L1) and 2 threads/node (L2)
// with shfl_xor combines — round-4 thread-per-node gave <1 wave/SIMD.
//
// Workspace: nodef[N float4] | cnt[N] | ovfcnt[1] | colsrc[K*N] |
//            ovfd[OVF_MAX] | ovfs[OVF_MAX]
// ---------------------------------------------------------------------------

// K1: single edge pass — rank via atomic count, write transposed slab.
__global__ void k_scatter(const int* __restrict__ esrc, const int* __restrict__ edst,
                          int* __restrict__ cnt, int* __restrict__ colsrc,
                          int* __restrict__ ovfcnt, int* __restrict__ ovfd,
                          int* __restrict__ ovfs, float* __restrict__ out,
                          int E, int N) {
    int j = blockIdx.x * blockDim.x + threadIdx.x;
    if (j == 0) { out[0] = 0.f; out[1] = 0.f; }
    if (j >= E) return;
    int d = edst[j];
    int s = esrc[j];
    int r = atomicAdd(&cnt[d], 1);
    if (r < K_SLAB) {
        colsrc[r * N + d] = s;
    } else {
        int p = atomicAdd(ovfcnt, 1);
        if (p < OVF_MAX) { ovfd[p] = d; ovfs[p] = s; }
    }
}

// K2: layer-1 gather + rank-1 expansion + ReLU + 512x2 GEMV.
// 4 threads per node: edge loop strided by sub, den/num combined via
// shfl_xor(1,2); GEMV strided idx%4==sub (consecutive banks, no conflict),
// h20/h21 combined the same way. Per-head consts computed per block in LDS.
// Softmax shift-invariance: max-subtraction skipped (|e| small, fp32 exp ok).
__global__ __launch_bounds__(256) void k_gather1(
        const int* __restrict__ cnt, const int* __restrict__ colsrc,
        const int* __restrict__ ovfcnt, const int* __restrict__ ovfd,
        const int* __restrict__ ovfs,
        const float* __restrict__ x,
        const float* __restrict__ W1, const float* __restrict__ as1,
        const float* __restrict__ ad1, const float* __restrict__ b1,
        const float* __restrict__ W2, const float* __restrict__ as2,
        const float* __restrict__ ad2,
        float4* __restrict__ nodef, int N) {
    __shared__ float sW1[512], sB1[512], sW2[1024], sconsts[16];
    for (int t = threadIdx.x; t < 512; t += 256) { sW1[t] = W1[t]; sB1[t] = b1[t]; }
    for (int t = threadIdx.x; t < 1024; t += 256) sW2[t] = W2[t];
    if (threadIdx.x < 16) {
        int h = threadIdx.x & 7;
        const float* a = (threadIdx.x < 8) ? as1 : ad1;
        float acc = 0.f;
        #pragma unroll
        for (int f = 0; f < 64; ++f) acc += W1[h * 64 + f] * a[h * 64 + f];
        sconsts[threadIdx.x] = acc;
    }
    __syncthreads();
    int t = blockIdx.x * blockDim.x + threadIdx.x;
    int n = t >> 2, sub = t & 3;
    if (n >= N) return;
    float cs[8], cd[8];
    #pragma unroll
    for (int h = 0; h < 8; ++h) { cs[h] = sconsts[h]; cd[h] = sconsts[8 + h]; }
    float xd = x[n];
    float den[8] = {0,0,0,0,0,0,0,0}, num[8] = {0,0,0,0,0,0,0,0};
    if (sub == 0) {                       // self-loop
        #pragma unroll
        for (int h = 0; h < 8; ++h) {
            float e = fmaf(xd, cs[h], xd * cd[h]);
            e = e > 0.f ? e : LRELU_SLOPE * e;
            float ex = __expf(e);
            den[h] = ex; num[h] = ex * xd;
        }
    }
    int deg = cnt[n];
    int dcl = deg < K_SLAB ? deg : K_SLAB;
    for (int k = sub; k < dcl; k += 4) {
        float xs = x[colsrc[k * N + n]];
        #pragma unroll
        for (int h = 0; h < 8; ++h) {
            float e = fmaf(xs, cs[h], xd * cd[h]);
            e = e > 0.f ? e : LRELU_SLOPE * e;
            float ex = __expf(e);
            den[h] += ex; num[h] += ex * xs;
        }
    }
    if (deg > K_SLAB) {                   // overflow scan (empty in practice)
        int m = *ovfcnt; m = m < OVF_MAX ? m : OVF_MAX;
        for (int i = sub; i < m; i += 4) {
            if (ovfd[i] == n) {
                float xs = x[ovfs[i]];
                #pragma unroll
                for (int h = 0; h < 8; ++h) {
                    float e = fmaf(xs, cs[h], xd * cd[h]);
                    e = e > 0.f ? e : LRELU_SLOPE * e;
                    float ex = __expf(e);
                    den[h] += ex; num[h] += ex * xs;
                }
            }
        }
    }
    #pragma unroll
    for (int off = 1; off < 4; off <<= 1) {
        #pragma unroll
        for (int h = 0; h < 8; ++h) {
            den[h] += __shfl_xor(den[h], off);
            num[h] += __shfl_xor(num[h], off);
        }
    }
    float sh[8];
    #pragma unroll
    for (int h = 0; h < 8; ++h) sh[h] = num[h] / (den[h] + 1e-16f);
    float h20 = 0.f, h21 = 0.f;
    for (int idx = sub; idx < 512; idx += 4) {
        int h = idx >> 6;
        float v = fmaf(sW1[idx], sh[h], sB1[idx]);
        v = fmaxf(v, 0.f);
        h20 = fmaf(v, sW2[2 * idx], h20);
        h21 = fmaf(v, sW2[2 * idx + 1], h21);
    }
    #pragma unroll
    for (int off = 1; off < 4; off <<= 1) {
        h20 += __shfl_xor(h20, off);
        h21 += __shfl_xor(h21, off);
    }
    if (sub == 0) {
        float as_ = h20 * as2[0] + h21 * as2[1];
        float ad_ = h20 * ad2[0] + h21 * ad2[1];
        float4 o; o.x = h20; o.y = h21; o.z = as_; o.w = ad_;
        nodef[n] = o;
    }
}

// K3: layer-2 gather + log_softmax + mean reduction. 2 threads per node.
__global__ __launch_bounds__(256) void k_gather2(
        const int* __restrict__ cnt, const int* __restrict__ colsrc,
        const int* __restrict__ ovfcnt, const int* __restrict__ ovfd,
        const int* __restrict__ ovfs,
        const float4* __restrict__ nodef, const float* __restrict__ b2,
        float* __restrict__ out, int N) {
    int t = blockIdx.x * blockDim.x + threadIdx.x;
    int n = t >> 1, sub = t & 1;
    float l0 = 0.f, l1 = 0.f;
    if (n < N) {
        float4 fd = nodef[n];
        float den = 0.f, n0 = 0.f, n1 = 0.f;
        if (sub == 0) {                   // self-loop
            float e = fd.z + fd.w;
            e = e > 0.f ? e : LRELU_SLOPE * e;
            float ex = __expf(e);
            den = ex; n0 = ex * fd.x; n1 = ex * fd.y;
        }
        int deg = cnt[n];
        int dcl = deg < K_SLAB ? deg : K_SLAB;
        for (int k = sub; k < dcl; k += 2) {
            float4 fs = nodef[colsrc[k * N + n]];
            float e = fs.z + fd.w;
            e = e > 0.f ? e : LRELU_SLOPE * e;
            float ex = __expf(e);
            den += ex; n0 += ex * fs.x; n1 += ex * fs.y;
        }
        if (deg > K_SLAB) {
            int m = *ovfcnt; m = m < OVF_MAX ? m : OVF_MAX;
            for (int i = sub; i < m; i += 2) {
                if (ovfd[i] == n) {
                    float4 fs = nodef[ovfs[i]];
                    float e = fs.z + fd.w;
                    e = e > 0.f ? e : LRELU_SLOPE * e;
                    float ex = __expf(e);
                    den += ex; n0 += ex * fs.x; n1 += ex * fs.y;
                }
            }
        }
        den += __shfl_xor(den, 1);
        n0  += __shfl_xor(n0, 1);
        n1  += __shfl_xor(n1, 1);
        if (sub == 0) {
            float inv = 1.f / (den + 1e-16f);
            float o0 = n0 * inv + b2[0];
            float o1 = n1 * inv + b2[1];
            float m = fmaxf(o0, o1);
            float z0 = o0 - m, z1 = o1 - m;
            float lse = logf(__expf(z0) + __expf(z1));
            l0 = z0 - lse; l1 = z1 - lse;
        }
    }
    #pragma unroll
    for (int off = 32; off; off >>= 1) {
        l0 += __shfl_down(l0, off);
        l1 += __shfl_down(l1, off);
    }
    __shared__ float w0[4], w1[4];
    int wid = threadIdx.x >> 6, lane = threadIdx.x & 63;
    if (lane == 0) { w0[wid] = l0; w1[wid] = l1; }
    __syncthreads();
    if (threadIdx.x == 0) {
        float s0 = w0[0] + w0[1] + w0[2] + w0[3];
        float s1 = w1[0] + w1[1] + w1[2] + w1[3];
        float invN = 1.f / (float)N;
        atomicAdd(&out[0], s0 * invN);
        atomicAdd(&out[1], s1 * invN);
    }
}

extern "C" void kernel_launch(void* const* d_in, const int* in_sizes, int n_in,
                              void* d_out, int out_size, void* d_ws, size_t ws_size,
                              hipStream_t stream) {
    const float* x   = (const float*)d_in[0];
    const int*   ei  = (const int*)d_in[1];
    const float* W1  = (const float*)d_in[2];
    const float* as1 = (const float*)d_in[3];
    const float* ad1 = (const float*)d_in[4];
    const float* b1  = (const float*)d_in[5];
    const float* W2  = (const float*)d_in[6];
    const float* as2 = (const float*)d_in[7];
    const float* ad2 = (const float*)d_in[8];
    const float* b2  = (const float*)d_in[9];
    int N = in_sizes[0];       // 50000
    int E = in_sizes[1] / 2;   // 400000
    float* out = (float*)d_out;

    char* ws = (char*)d_ws;
    float4* nodef  = (float4*)ws;                    // N float4
    int*    cnt    = (int*)(ws + (size_t)N * 16);    // N
    int*    ovfcnt = cnt + N;                        // 1
    int*    colsrc = ovfcnt + 1;                     // K_SLAB*N
    int*    ovfd   = colsrc + (size_t)K_SLAB * N;    // OVF_MAX
    int*    ovfs   = ovfd + OVF_MAX;                 // OVF_MAX

    const int* esrc = ei;
    const int* edst = ei + E;

    // zero cnt + ovfcnt (one fill dispatch)
    hipMemsetAsync(cnt, 0, (size_t)(N + 1) * sizeof(int), stream);

    int eb = (E + 255) / 256;
    hipLaunchKernelGGL(k_scatter, dim3(eb), dim3(256), 0, stream,
                       esrc, edst, cnt, colsrc, ovfcnt, ovfd, ovfs, out, E, N);

    int g1b = (4 * N + 255) / 256;
    hipLaunchKernelGGL(k_gather1, dim3(g1b), dim3(256), 0, stream,
                       cnt, colsrc, ovfcnt, ovfd, ovfs, x,
                       W1, as1, ad1, b1, W2, as2, ad2, nodef, N);

    int g2b = (2 * N + 255) / 256;
    hipLaunchKernelGGL(k_gather2, dim3(g2b), dim3(256), 0, stream,
                       cnt, colsrc, ovfcnt, ovfd, ovfs, nodef, b2, out, N);
}

// Round 9
// 141.010 us; speedup vs baseline: 3.3169x; 1.1326x over previous
//
#include <hip/hip_runtime.h>

#define LRELU_SLOPE 0.2f
#define K_SLAB 40
#define OVF_MAX 8192

// ---------------------------------------------------------------------------
// 4-dispatch gather GAT.
// Round-8 lesson: k_gather1 ran at VGPR_Count=36 — its ~40 floats of
// per-thread arrays were in SCRATCH (sh[h] runtime-indexed in the GEMV loop
// made the compiler demote; local-mem RMW per edge/GEMV iteration = 47.6us).
// Fix: h is the OUTER fully-unrolled loop everywhere (all array indices
// compile-time), float4 LDS reads with static offsets, 8 threads/node.
//
// Round-6 lesson (kept): no cooperative grid.sync (~100us/barrier on gfx950);
// kernel-launch boundaries are the cheap barrier.
// Transposed slab colsrc[rank*N+d] (K=40, Poisson(8) in-degree; overflow
// list for correctness, empty in practice) -> coalesced gather reads.
//
// Workspace: nodef[N float4] | cnt[N] | ovfcnt[1] | colsrc[K*N] |
//            ovfd[OVF_MAX] | ovfs[OVF_MAX]
// ---------------------------------------------------------------------------

// K1: single edge pass — rank via atomic count, write transposed slab.
__global__ void k_scatter(const int* __restrict__ esrc, const int* __restrict__ edst,
                          int* __restrict__ cnt, int* __restrict__ colsrc,
                          int* __restrict__ ovfcnt, int* __restrict__ ovfd,
                          int* __restrict__ ovfs, float* __restrict__ out,
                          int E, int N) {
    int j = blockIdx.x * blockDim.x + threadIdx.x;
    if (j == 0) { out[0] = 0.f; out[1] = 0.f; }
    if (j >= E) return;
    int d = edst[j];
    int s = esrc[j];
    int r = atomicAdd(&cnt[d], 1);
    if (r < K_SLAB) {
        colsrc[r * N + d] = s;
    } else {
        int p = atomicAdd(ovfcnt, 1);
        if (p < OVF_MAX) { ovfd[p] = d; ovfs[p] = s; }
    }
}

// K2: layer-1 gather + rank-1 expansion + ReLU + 512x2 GEMV.
// 8 threads/node. All per-thread arrays accessed ONLY with static indices
// (h outer, fully unrolled) -> registers, no scratch. GEMV reads LDS as
// float4 at q = h*16 + sub*2 + j (8 lanes span 128B contiguous, conflict-
// free; 8 node-groups broadcast). Softmax max-subtraction skipped
// (shift-invariant, |e| small enough for fp32 exp).
__global__ __launch_bounds__(256) void k_gather1(
        const int* __restrict__ cnt, const int* __restrict__ colsrc,
        const int* __restrict__ ovfcnt, const int* __restrict__ ovfd,
        const int* __restrict__ ovfs,
        const float* __restrict__ x,
        const float* __restrict__ W1, const float* __restrict__ as1,
        const float* __restrict__ ad1, const float* __restrict__ b1,
        const float* __restrict__ W2, const float* __restrict__ as2,
        const float* __restrict__ ad2,
        float4* __restrict__ nodef, int N) {
    __shared__ float sW1[512], sB1[512], sW2[1024], sconsts[16];
    for (int t = threadIdx.x; t < 512; t += 256) { sW1[t] = W1[t]; sB1[t] = b1[t]; }
    for (int t = threadIdx.x; t < 1024; t += 256) sW2[t] = W2[t];
    if (threadIdx.x < 16) {
        int h = threadIdx.x & 7;
        const float* a = (threadIdx.x < 8) ? as1 : ad1;
        float acc = 0.f;
        #pragma unroll
        for (int f = 0; f < 64; ++f) acc += W1[h * 64 + f] * a[h * 64 + f];
        sconsts[threadIdx.x] = acc;
    }
    __syncthreads();
    int t = blockIdx.x * blockDim.x + threadIdx.x;
    int n = t >> 3, sub = t & 7;
    if (n >= N) return;

    float cs[8], cd[8];
    #pragma unroll
    for (int h = 0; h < 8; ++h) { cs[h] = sconsts[h]; cd[h] = sconsts[8 + h]; }
    float xd = x[n];
    float den[8], num[8];
    #pragma unroll
    for (int h = 0; h < 8; ++h) { den[h] = 0.f; num[h] = 0.f; }

    if (sub == 0) {                       // self-loop
        #pragma unroll
        for (int h = 0; h < 8; ++h) {
            float e = fmaf(xd, cs[h], xd * cd[h]);
            e = e > 0.f ? e : LRELU_SLOPE * e;
            float ex = __expf(e);
            den[h] = ex; num[h] = ex * xd;
        }
    }
    int deg = cnt[n];
    int dcl = deg < K_SLAB ? deg : K_SLAB;
    for (int k = sub; k < dcl; k += 8) {
        float xs = x[colsrc[k * N + n]];
        #pragma unroll
        for (int h = 0; h < 8; ++h) {
            float e = fmaf(xs, cs[h], xd * cd[h]);
            e = e > 0.f ? e : LRELU_SLOPE * e;
            float ex = __expf(e);
            den[h] += ex; num[h] += ex * xs;
        }
    }
    if (deg > K_SLAB) {                   // overflow scan (empty in practice)
        int m = *ovfcnt; m = m < OVF_MAX ? m : OVF_MAX;
        for (int i = sub; i < m; i += 8) {
            if (ovfd[i] == n) {
                float xs = x[ovfs[i]];
                #pragma unroll
                for (int h = 0; h < 8; ++h) {
                    float e = fmaf(xs, cs[h], xd * cd[h]);
                    e = e > 0.f ? e : LRELU_SLOPE * e;
                    float ex = __expf(e);
                    den[h] += ex; num[h] += ex * xs;
                }
            }
        }
    }
    // combine the 8-lane group (xor masks 1,2,4 stay within the group)
    #pragma unroll
    for (int off = 1; off < 8; off <<= 1) {
        #pragma unroll
        for (int h = 0; h < 8; ++h) {
            den[h] += __shfl_xor(den[h], off);
            num[h] += __shfl_xor(num[h], off);
        }
    }
    float sh[8];
    #pragma unroll
    for (int h = 0; h < 8; ++h) sh[h] = num[h] / (den[h] + 1e-16f);

    // GEMV: head-outer (static sh index), float4 LDS reads, static offsets.
    const float4* W1v = (const float4*)sW1;
    const float4* B1v = (const float4*)sB1;
    const float4* W2v = (const float4*)sW2;
    float h20 = 0.f, h21 = 0.f;
    #pragma unroll
    for (int h = 0; h < 8; ++h) {
        float s = sh[h];
        #pragma unroll
        for (int j = 0; j < 2; ++j) {
            int q = h * 16 + sub * 2 + j;
            float4 a  = W1v[q];
            float4 b  = B1v[q];
            float4 wl = W2v[2 * q];
            float4 wh = W2v[2 * q + 1];
            float v0 = fmaxf(fmaf(a.x, s, b.x), 0.f);
            float v1 = fmaxf(fmaf(a.y, s, b.y), 0.f);
            float v2 = fmaxf(fmaf(a.z, s, b.z), 0.f);
            float v3 = fmaxf(fmaf(a.w, s, b.w), 0.f);
            h20 = fmaf(v0, wl.x, h20); h21 = fmaf(v0, wl.y, h21);
            h20 = fmaf(v1, wl.z, h20); h21 = fmaf(v1, wl.w, h21);
            h20 = fmaf(v2, wh.x, h20); h21 = fmaf(v2, wh.y, h21);
            h20 = fmaf(v3, wh.z, h20); h21 = fmaf(v3, wh.w, h21);
        }
    }
    #pragma unroll
    for (int off = 1; off < 8; off <<= 1) {
        h20 += __shfl_xor(h20, off);
        h21 += __shfl_xor(h21, off);
    }
    if (sub == 0) {
        float as_ = h20 * as2[0] + h21 * as2[1];
        float ad_ = h20 * ad2[0] + h21 * ad2[1];
        float4 o; o.x = h20; o.y = h21; o.z = as_; o.w = ad_;
        nodef[n] = o;
    }
}

// K3: layer-2 gather + log_softmax + mean reduction. 4 threads per node.
__global__ __launch_bounds__(256) void k_gather2(
        const int* __restrict__ cnt, const int* __restrict__ colsrc,
        const int* __restrict__ ovfcnt, const int* __restrict__ ovfd,
        const int* __restrict__ ovfs,
        const float4* __restrict__ nodef, const float* __restrict__ b2,
        float* __restrict__ out, int N) {
    int t = blockIdx.x * blockDim.x + threadIdx.x;
    int n = t >> 2, sub = t & 3;
    float l0 = 0.f, l1 = 0.f;
    if (n < N) {
        float4 fd = nodef[n];
        float den = 0.f, n0 = 0.f, n1 = 0.f;
        if (sub == 0) {                   // self-loop
            float e = fd.z + fd.w;
            e = e > 0.f ? e : LRELU_SLOPE * e;
            float ex = __expf(e);
            den = ex; n0 = ex * fd.x; n1 = ex * fd.y;
        }
        int deg = cnt[n];
        int dcl = deg < K_SLAB ? deg : K_SLAB;
        for (int k = sub; k < dcl; k += 4) {
            float4 fs = nodef[colsrc[k * N + n]];
            float e = fs.z + fd.w;
            e = e > 0.f ? e : LRELU_SLOPE * e;
            float ex = __expf(e);
            den += ex; n0 += ex * fs.x; n1 += ex * fs.y;
        }
        if (deg > K_SLAB) {
            int m = *ovfcnt; m = m < OVF_MAX ? m : OVF_MAX;
            for (int i = sub; i < m; i += 4) {
                if (ovfd[i] == n) {
                    float4 fs = nodef[ovfs[i]];
                    float e = fs.z + fd.w;
                    e = e > 0.f ? e : LRELU_SLOPE * e;
                    float ex = __expf(e);
                    den += ex; n0 += ex * fs.x; n1 += ex * fs.y;
                }
            }
        }
        #pragma unroll
        for (int off = 1; off < 4; off <<= 1) {
            den += __shfl_xor(den, off);
            n0  += __shfl_xor(n0, off);
            n1  += __shfl_xor(n1, off);
        }
        if (sub == 0) {
            float inv = 1.f / (den + 1e-16f);
            float o0 = n0 * inv + b2[0];
            float o1 = n1 * inv + b2[1];
            float m = fmaxf(o0, o1);
            float z0 = o0 - m, z1 = o1 - m;
            float lse = logf(__expf(z0) + __expf(z1));
            l0 = z0 - lse; l1 = z1 - lse;
        }
    }
    #pragma unroll
    for (int off = 32; off; off >>= 1) {
        l0 += __shfl_down(l0, off);
        l1 += __shfl_down(l1, off);
    }
    __shared__ float w0[4], w1[4];
    int wid = threadIdx.x >> 6, lane = threadIdx.x & 63;
    if (lane == 0) { w0[wid] = l0; w1[wid] = l1; }
    __syncthreads();
    if (threadIdx.x == 0) {
        float s0 = w0[0] + w0[1] + w0[2] + w0[3];
        float s1 = w1[0] + w1[1] + w1[2] + w1[3];
        float invN = 1.f / (float)N;
        atomicAdd(&out[0], s0 * invN);
        atomicAdd(&out[1], s1 * invN);
    }
}

extern "C" void kernel_launch(void* const* d_in, const int* in_sizes, int n_in,
                              void* d_out, int out_size, void* d_ws, size_t ws_size,
                              hipStream_t stream) {
    const float* x   = (const float*)d_in[0];
    const int*   ei  = (const int*)d_in[1];
    const float* W1  = (const float*)d_in[2];
    const float* as1 = (const float*)d_in[3];
    const float* ad1 = (const float*)d_in[4];
    const float* b1  = (const float*)d_in[5];
    const float* W2  = (const float*)d_in[6];
    const float* as2 = (const float*)d_in[7];
    const float* ad2 = (const float*)d_in[8];
    const float* b2  = (const float*)d_in[9];
    int N = in_sizes[0];       // 50000
    int E = in_sizes[1] / 2;   // 400000
    float* out = (float*)d_out;

    char* ws = (char*)d_ws;
    float4* nodef  = (float4*)ws;                    // N float4
    int*    cnt    = (int*)(ws + (size_t)N * 16);    // N
    int*    ovfcnt = cnt + N;                        // 1
    int*    colsrc = ovfcnt + 1;                     // K_SLAB*N
    int*    ovfd   = colsrc + (size_t)K_SLAB * N;    // OVF_MAX
    int*    ovfs   = ovfd + OVF_MAX;                 // OVF_MAX

    const int* esrc = ei;
    const int* edst = ei + E;

    // zero cnt + ovfcnt (one fill dispatch)
    hipMemsetAsync(cnt, 0, (size_t)(N + 1) * sizeof(int), stream);

    int eb = (E + 255) / 256;
    hipLaunchKernelGGL(k_scatter, dim3(eb), dim3(256), 0, stream,
                       esrc, edst, cnt, colsrc, ovfcnt, ovfd, ovfs, out, E, N);

    int g1b = (8 * N + 255) / 256;
    hipLaunchKernelGGL(k_gather1, dim3(g1b), dim3(256), 0, stream,
                       cnt, colsrc, ovfcnt, ovfd, ovfs, x,
                       W1, as1, ad1, b1, W2, as2, ad2, nodef, N);

    int g2b = (4 * N + 255) / 256;
    hipLaunchKernelGGL(k_gather2, dim3(g2b), dim3(256), 0, stream,
                       cnt, colsrc, ovfcnt, ovfd, ovfs, nodef, b2, out, N);
}